// Round 12
// baseline (455.492 us; speedup 1.0000x reference)
//
#include <hip/hip_runtime.h>

typedef _Float16 half8 __attribute__((ext_vector_type(8)));
typedef _Float16 half4 __attribute__((ext_vector_type(4)));
typedef float f32x4 __attribute__((ext_vector_type(4)));
typedef float f32x16 __attribute__((ext_vector_type(16)));

#define CHUNK 1024
#define NCHUNK_MAX 512  // supports up to 524288 atoms in compact mode

// ---------------- prologue: weights retile + chunk-local compaction --------
// One dispatch, two block roles:
//   blocks [0, nprep): cast + retile weights to fp16 MFMA tiles.
//   blocks [nprep, nprep+nchunks): chunk c (1024 atoms) self-compacts into
//     idxloc[c*1024 ...] and writes cnt[c]. No atomics -> no memset, no
//     extra dispatch (R15: each dispatch costs ~25us on this bench).
__global__ void prep_compact(const float* __restrict__ W1, const float* __restrict__ W2,
                             const float* __restrict__ W3, const float* __restrict__ W4,
                             _Float16* __restrict__ wt1, _Float16* __restrict__ wt2,
                             _Float16* __restrict__ wt3, _Float16* __restrict__ w4h,
                             const int* __restrict__ species, int* __restrict__ idxloc,
                             int* __restrict__ cnt, float* __restrict__ out,
                             int natoms, int nprep) {
  __shared__ int wsum[4];
  if (blockIdx.x >= nprep) {
    // ---- chunk-local compaction: 1024 atoms, 256 threads, 4 sub-rounds ----
    const int c = blockIdx.x - nprep;
    const int lane = threadIdx.x & 63, w = threadIdx.x >> 6;
    int base = 0;
#pragma unroll 1
    for (int j = 0; j < 4; ++j) {
      const int i = c * CHUNK + j * 256 + threadIdx.x;
      const bool valid = (i < natoms) && (species[i] >= 0);
      const unsigned long long m = __ballot(valid);
      if (lane == 0) wsum[w] = (int)__popcll(m);
      __syncthreads();
      int wb = base;
#pragma unroll
      for (int k = 0; k < 4; ++k)
        if (k < w) wb += wsum[k];
      if (valid) {
        int off = (int)__popcll(m & ((1ull << lane) - 1));
        idxloc[c * CHUNK + wb + off] = i;
      } else if (i < natoms) {
        out[i] = 0.0f;  // masked atoms must be exactly 0
      }
      base += wsum[0] + wsum[1] + wsum[2] + wsum[3];
      __syncthreads();  // wsum reused next round
    }
    if (threadIdx.x == 0) cnt[c] = base;
    return;
  }
  // ---- weight retile (unchanged math) ----
  int idx = blockIdx.x * blockDim.x + threadIdx.x;
  if (idx < 512 * 256) {  // W1: K=256, N=512, KS=16
    int k = idx >> 9, n = idx & 511;
    int off = (((n >> 5) * 16 + (k >> 4)) << 9) + (n & 31) * 8 + (((k >> 3) & 1) << 8) + (k & 7);
    wt1[off] = (_Float16)W1[idx];
    return;
  }
  int i2 = idx - 512 * 256;
  if (i2 < 512 * 512) {  // W2: K=512, N=512, KS=32
    int k = i2 >> 9, n = i2 & 511;
    int off = (((n >> 5) * 32 + (k >> 4)) << 9) + (n & 31) * 8 + (((k >> 3) & 1) << 8) + (k & 7);
    wt2[off] = (_Float16)W2[i2];
    return;
  }
  int i3 = i2 - 512 * 512;
  if (i3 < 512 * 256) {  // W3: K=512, N=256, KS=32
    int k = i3 >> 8, n = i3 & 255;
    int off = (((n >> 5) * 32 + (k >> 4)) << 9) + (n & 31) * 8 + (((k >> 3) & 1) << 8) + (k & 7);
    wt3[off] = (_Float16)W3[i3];
    return;
  }
  int i4 = i3 - 512 * 256;
  if (i4 < 256) w4h[i4] = (_Float16)W4[i4];
}

// silu with raw v_rcp_f32 (no IEEE div sequence); ~1ulp, well within tolerance
__device__ __forceinline__ float fast_silu(float s) {
  float e = __expf(-s);
  float d = 1.0f + e;
  float r;
  asm("v_rcp_f32 %0, %1" : "=v"(r) : "v"(d));
  return s * r;
}

// ---------------- fused MLP ----------------
// R8 geometry (verified local optimum): 64 atoms/block, 512 threads = 8
// waves, FT=2, AT=2, acc 64 AGPR + 64 arch VGPR = exactly the 128-reg
// budget at 4 waves/EU; 2 blocks/CU -> 16 waves/CU in TWO independent
// barrier domains (R13: merging them costs 16%).
// Evidence: R9 FAILED (L3 prefetch thrash). R10 NEUTRAL (kept). R11
// falsified skew. R12 falsified 8 waves/CU. R13 falsified single-domain.
// R14 FAILED (in_sizes is elements). R15: dispatches cost ~25us each.
// R16 WIN (360): dispatch-free compaction. R17 WIN (352.6): CHUNK=1024 +
// L4 fused into L3 epilogue. R18 small WIN (350.3): NT X-loads. R19 WIN
// (343.9): cross-layer A-prefetch (layer-entry latency hidden under
// epilogues; VGPR held at 64).
// R20 (this round): recalibrated model — MFMA pipe demand is ~33k of
// ~100k cyc/SIMD/generation (MfmaUtil 40 is REAL demand), so remaining
// levers are issue-quality. The K-loops carried `#pragma unroll 1`
// (inherited): ~15 runtime-VALU per ks-pair (A base adds, B XOR adds,
// loop ctrl) compete with MFMA for the SIMD issue port. unroll 4 folds
// A addresses into immediate offsets (A has no swizzle) and quarters
// loop control; launch_bounds(512,4) pins the register budget so the
// unroll cannot silently cost occupancy.

#define MFMA(a, b, c) __builtin_amdgcn_mfma_f32_32x32x16_f16(a, b, c, 0, 0, 0)

// A0: preloaded first A-fragments (ks=0) for THIS layer.
// If NFT>0: before the epilogue, load next layer's first A-fragments
// (wfeat stride NKS) into Anext.
template <int FT, int AT, int KS, int PIN, int POUT, int NFT, int NKS>
__device__ __forceinline__ void layer(const _Float16* __restrict__ wt,
                                      const float* __restrict__ bias,
                                      char* __restrict__ Hb,
                                      int wfeat, int lane,
                                      const half8* __restrict__ A0,
                                      const _Float16* __restrict__ next_wt,
                                      half8* __restrict__ Anext) {
  const int lr = lane & 31;
  const int lh = lane >> 5;
  const int n0 = wfeat * (FT * 32);
  const int s0 = (lr & 31) << 4;  // row swizzle; (a*32+lr)&31 == lr&31
  const char* Bp = Hb + lr * PIN;
  const char* wp = (const char*)wt + (size_t)(wfeat * FT * KS) * 1024 + lh * 512 + lr * 16;

  // init acc = bias (folds epilogue bias-add into MFMA C-in; bv transient)
  f32x16 acc[FT][AT];
#pragma unroll
  for (int f = 0; f < FT; ++f)
#pragma unroll
    for (int rg = 0; rg < 4; ++rg) {
      const int feat = n0 + f * 32 + rg * 8 + lh * 4;
      const f32x4 bv = *(const f32x4*)(bias + feat);
#pragma unroll
      for (int a = 0; a < AT; ++a)
#pragma unroll
        for (int r = 0; r < 4; ++r) acc[f][a][rg * 4 + r] = bv[r];
    }

  half8 Af[FT], Ag[FT], Bf[AT], Bg[AT];
#pragma unroll
  for (int f = 0; f < FT; ++f) Af[f] = A0[f];  // preloaded (R19)
#pragma unroll
  for (int a = 0; a < AT; ++a)
    Bf[a] = *(const half8*)(Bp + a * 32 * PIN + ((lh * 16) ^ s0));

  // R20: unroll 4 — A offsets become compile-time immediates within each
  // macro-iteration; B keeps its XOR (swizzle bits overlap ks-stride bits).
#pragma unroll 4
  for (int ks = 0; ks < KS - 2; ks += 2) {
#pragma unroll
    for (int f = 0; f < FT; ++f)
      Ag[f] = *(const half8*)(wp + f * (KS * 1024) + (ks + 1) * 1024);
#pragma unroll
    for (int a = 0; a < AT; ++a)
      Bg[a] = *(const half8*)(Bp + a * 32 * PIN + (((ks + 1) * 32 + lh * 16) ^ s0));
#pragma unroll
    for (int f = 0; f < FT; ++f)
#pragma unroll
      for (int a = 0; a < AT; ++a) acc[f][a] = MFMA(Af[f], Bf[a], acc[f][a]);
#pragma unroll
    for (int f = 0; f < FT; ++f)
      Af[f] = *(const half8*)(wp + f * (KS * 1024) + (ks + 2) * 1024);
#pragma unroll
    for (int a = 0; a < AT; ++a)
      Bf[a] = *(const half8*)(Bp + a * 32 * PIN + (((ks + 2) * 32 + lh * 16) ^ s0));
#pragma unroll
    for (int f = 0; f < FT; ++f)
#pragma unroll
      for (int a = 0; a < AT; ++a) acc[f][a] = MFMA(Ag[f], Bg[a], acc[f][a]);
  }
#pragma unroll
  for (int f = 0; f < FT; ++f)
    Ag[f] = *(const half8*)(wp + f * (KS * 1024) + (KS - 1) * 1024);
#pragma unroll
  for (int a = 0; a < AT; ++a)
    Bg[a] = *(const half8*)(Bp + a * 32 * PIN + ((((KS - 1) * 32) + lh * 16) ^ s0));
#pragma unroll
  for (int f = 0; f < FT; ++f)
#pragma unroll
    for (int a = 0; a < AT; ++a) acc[f][a] = MFMA(Af[f], Bf[a], acc[f][a]);
#pragma unroll
  for (int f = 0; f < FT; ++f)
#pragma unroll
    for (int a = 0; a < AT; ++a) acc[f][a] = MFMA(Ag[f], Bg[a], acc[f][a]);

  // R19: issue next layer's first A-loads NOW — latency hides under the
  // silu + barrier + epilogue-write phase. Buffer regs Af/Ag are dead
  // after the tail; Anext reuses that budget.
  if constexpr (NFT > 0) {
    const char* wpn = (const char*)next_wt + (size_t)(wfeat * NFT * NKS) * 1024 + lh * 512 + lr * 16;
#pragma unroll
    for (int f = 0; f < NFT; ++f)
      Anext[f] = *(const half8*)(wpn + f * (NKS * 1024));
  }

  // silu in-place BEFORE the barrier (R10).
#pragma unroll
  for (int f = 0; f < FT; ++f)
#pragma unroll
    for (int a = 0; a < AT; ++a)
#pragma unroll
      for (int j = 0; j < 16; ++j) acc[f][a][j] = fast_silu(acc[f][a][j]);

  __syncthreads();  // all waves done reading input region; safe to overwrite

  // post-barrier: cvt -> fp16, write swizzled (2-way, free)
#pragma unroll
  for (int f = 0; f < FT; ++f) {
#pragma unroll
    for (int rg = 0; rg < 4; ++rg) {
      const int feat = n0 + f * 32 + rg * 8 + lh * 4;
#pragma unroll
      for (int a = 0; a < AT; ++a) {
        half4 h;
#pragma unroll
        for (int r = 0; r < 4; ++r) h[r] = (_Float16)acc[f][a][rg * 4 + r];
        const int row = a * 32 + lr;
        *(half4*)(Hb + row * POUT + ((feat * 2) ^ ((row & 31) << 4))) = h;
      }
    }
  }
}

extern "C" __global__ void __launch_bounds__(512, 4)
mlp_kernel(const float* __restrict__ X, const int* __restrict__ species,
           const _Float16* __restrict__ wt1, const float* __restrict__ b1,
           const _Float16* __restrict__ wt2, const float* __restrict__ b2,
           const _Float16* __restrict__ wt3, const float* __restrict__ b3,
           const _Float16* __restrict__ w4h, const float* __restrict__ b4,
           float* __restrict__ out, int natoms,
           const int* __restrict__ idxloc, const int* __restrict__ cnt, int nchunks) {
  __shared__ __align__(16) char H[64 * 1024];
  __shared__ int prefixS[NCHUNK_MAX + 1];  // exclusive chunk starts
  __shared__ int gidx[64];                 // source atom per staged row
  __shared__ int wtot[8];
  const int tid = threadIdx.x;
  const int lane = tid & 63;
  const int wid = tid >> 6;  // 8 feature-slice waves
  const long abase = (long)blockIdx.x * 64;

  // R19: L1 first-A preload at kernel entry — latency hides under the
  // scan + staging phase. Harmless for early-exit blocks.
  half8 A1[2], A2[2], A3[1];
  {
    const char* wp1 = (const char*)wt1 + (size_t)(wid * 2 * 16) * 1024 +
                      (lane >> 5) * 512 + (lane & 31) * 16;
    A1[0] = *(const half8*)(wp1);
    A1[1] = *(const half8*)(wp1 + 16 * 1024);
  }

  int nvalid = natoms;
  if (idxloc) {
    // ---- per-block prefix scan of cnt[] (nchunks <= 512, 1 per thread) ----
    int v = (tid < nchunks) ? cnt[tid] : 0;
    int ws_ = v;
#pragma unroll
    for (int d = 1; d < 64; d <<= 1) {
      int o = __shfl_up(ws_, d);
      if (lane >= d) ws_ += o;
    }
    if (lane == 63) wtot[wid] = ws_;
    __syncthreads();
    int wbase = 0, tot = 0;
#pragma unroll
    for (int k = 0; k < 8; ++k) {
      if (k < wid) wbase += wtot[k];
      tot += wtot[k];
    }
    if (tid < nchunks) prefixS[tid] = wbase + ws_ - v;  // exclusive
    nvalid = tot;
    __syncthreads();  // prefixS ready
    if (abase >= nvalid) return;  // uniform whole-block exit
  }

  // ---- stage X[64x256] -> fp16 LDS, pitch 512B, swizzled ----
  // NT loads: X rows touched exactly once -> evict-first keeps weights
  // L2-resident (R18).
  {
    const int r = tid >> 3, cg = tid & 7;
    long li = abase + r;
    const long lmax = (long)nvalid - 1;
    if (li > lmax) li = lmax;  // clamp: pad rows read a valid row, never stored
    long g = li;
    if (idxloc) {
      int lo = 0, hi = nchunks - 1;  // largest c with prefixS[c] <= li
      while (lo < hi) {
        int mid = (lo + hi + 1) >> 1;
        if (prefixS[mid] <= (int)li) lo = mid; else hi = mid - 1;
      }
      g = idxloc[lo * CHUNK + ((int)li - prefixS[lo])];
      if (cg == 0) gidx[r] = (int)g;
    }
    const float* xp = X + g * 256;
    const int sw = (r & 31) << 4;
#pragma unroll
    for (int j = 0; j < 8; ++j) {
      const int colh = cg * 4 + j * 32;
      f32x4 v = __builtin_nontemporal_load((const f32x4*)(xp + colh));
      half4 h;
#pragma unroll
      for (int e = 0; e < 4; ++e) h[e] = (_Float16)v[e];
      *(half4*)(H + r * 512 + ((colh * 2) ^ sw)) = h;
    }
  }
  __syncthreads();

  // L1: Xh[64x256] -> H1[64x512]; prefetches L2's first A into A2
  layer<2, 2, 16, 512, 1024, 2, 32>(wt1, b1, H, wid, lane, A1, wt2, A2);
  __syncthreads();
  // L2: H1 -> H2[64x512]; prefetches L3's first A into A3
  layer<2, 2, 32, 1024, 1024, 1, 32>(wt2, b2, H, wid, lane, A2, wt3, A3);
  __syncthreads();

  // ---- L3 (FT=1, AT=2, KS=32) with L4 fused into the register epilogue ----
  {
    const int lr = lane & 31;
    const int lh = lane >> 5;
    const int n0 = wid * 32;
    const int s0 = (lr & 31) << 4;
    const char* Bp = H + lr * 1024;
    const char* wp = (const char*)wt3 + (size_t)(wid * 32) * 1024 + lh * 512 + lr * 16;

    f32x16 acc[2];
#pragma unroll
    for (int rg = 0; rg < 4; ++rg) {
      const int feat = n0 + rg * 8 + lh * 4;
      const f32x4 bv = *(const f32x4*)(b3 + feat);
#pragma unroll
      for (int a = 0; a < 2; ++a)
#pragma unroll
        for (int r = 0; r < 4; ++r) acc[a][rg * 4 + r] = bv[r];
    }

    half8 Af, Ag, Bf[2], Bg[2];
    Af = A3[0];  // preloaded by L2 (R19)
#pragma unroll
    for (int a = 0; a < 2; ++a)
      Bf[a] = *(const half8*)(Bp + a * 32 * 1024 + ((lh * 16) ^ s0));

#pragma unroll 4
    for (int ks = 0; ks < 30; ks += 2) {
      Ag = *(const half8*)(wp + (ks + 1) * 1024);
#pragma unroll
      for (int a = 0; a < 2; ++a)
        Bg[a] = *(const half8*)(Bp + a * 32 * 1024 + (((ks + 1) * 32 + lh * 16) ^ s0));
#pragma unroll
      for (int a = 0; a < 2; ++a) acc[a] = MFMA(Af, Bf[a], acc[a]);
      Af = *(const half8*)(wp + (ks + 2) * 1024);
#pragma unroll
      for (int a = 0; a < 2; ++a)
        Bf[a] = *(const half8*)(Bp + a * 32 * 1024 + (((ks + 2) * 32 + lh * 16) ^ s0));
#pragma unroll
      for (int a = 0; a < 2; ++a) acc[a] = MFMA(Ag, Bg[a], acc[a]);
    }
    Ag = *(const half8*)(wp + 31 * 1024);
#pragma unroll
    for (int a = 0; a < 2; ++a)
      Bg[a] = *(const half8*)(Bp + a * 32 * 1024 + ((31 * 32 + lh * 16) ^ s0));
#pragma unroll
    for (int a = 0; a < 2; ++a) acc[a] = MFMA(Af, Bf[a], acc[a]);
#pragma unroll
    for (int a = 0; a < 2; ++a) acc[a] = MFMA(Ag, Bg[a], acc[a]);

    // silu + in-register dot with w4 slice (feats n0+rg*8+lh*4+r)
    float s[2] = {0.0f, 0.0f};
#pragma unroll
    for (int rg = 0; rg < 4; ++rg) {
      half4 wv = *(const half4*)(w4h + n0 + rg * 8 + lh * 4);
#pragma unroll
      for (int r = 0; r < 4; ++r) {
        const float wf = (float)wv[r];
#pragma unroll
        for (int a = 0; a < 2; ++a)
          s[a] += fast_silu(acc[a][rg * 4 + r]) * wf;
      }
    }
    // combine the two feat-halves (lh=0/1) held by lanes lr and lr+32
    s[0] += __shfl_xor(s[0], 32);
    s[1] += __shfl_xor(s[1], 32);

    __syncthreads();  // all waves done reading H2 -> safe to overwrite with P
    float* P = (float*)H;  // P[atom][8] partials, 2KB
    if (lh == 0) {
      P[(0 * 32 + lr) * 8 + wid] = s[0];
      P[(1 * 32 + lr) * 8 + wid] = s[1];
    }
  }
  __syncthreads();

  // final reduce: out[atom] = sum_w P[atom][w] + b4
  {
    const float* P = (const float*)H;
    const int atom = tid >> 3, part = tid & 7;
    float sum = P[atom * 8 + part];
    sum += __shfl_xor(sum, 1);
    sum += __shfl_xor(sum, 2);
    sum += __shfl_xor(sum, 4);
    if (part == 0) {
      const long li = abase + atom;
      if (li < nvalid) {
        float r = sum + b4[0];
        if (idxloc) {
          __builtin_nontemporal_store(r, &out[gidx[atom]]);  // masked zeroed in prep
        } else {
          float v = (species[li] >= 0) ? r : 0.0f;
          __builtin_nontemporal_store(v, &out[li]);
        }
      }
    }
  }
}

extern "C" void kernel_launch(void* const* d_in, const int* in_sizes, int n_in,
                              void* d_out, int out_size, void* d_ws, size_t ws_size,
                              hipStream_t stream) {
  const float* X = (const float*)d_in[0];
  const int* species = (const int*)d_in[1];
  const float* W1 = (const float*)d_in[2];
  const float* b1 = (const float*)d_in[3];
  const float* W2 = (const float*)d_in[4];
  const float* b2 = (const float*)d_in[5];
  const float* W3 = (const float*)d_in[6];
  const float* b3 = (const float*)d_in[7];
  const float* W4 = (const float*)d_in[8];
  const float* b4 = (const float*)d_in[9];
  float* out = (float*)d_out;
  const int natoms = in_sizes[0] / 256;  // in_sizes is ELEMENTS (R14 lesson)

  char* ws = (char*)d_ws;
  _Float16* wt1 = (_Float16*)(ws);                             // 512*256*2 B
  _Float16* wt2 = (_Float16*)(ws + 262144);                    // 512*512*2 B
  _Float16* wt3 = (_Float16*)(ws + 262144 + 524288);           // 256*512*2 B
  _Float16* w4h = (_Float16*)(ws + 262144 + 524288 + 262144);  // 512 B
  int* cnt = (int*)(ws + 1049088);                             // nchunks*4 B
  int* idxloc = (int*)(ws + 1049088 + 4096);                   // natoms*4 B (padded region)

  const int nchunks = (natoms + CHUNK - 1) / CHUNK;
  const size_t ws_needed = 1049088 + 4096 + (size_t)nchunks * CHUNK * 4;
  const bool use_compact = (ws_size >= ws_needed) && (nchunks <= NCHUNK_MAX);

  const int prep_total = 512 * 256 + 512 * 512 + 256 * 512 + 256;
  const int nprep = (prep_total + 255) / 256;
  const int nblk = nprep + (use_compact ? nchunks : 0);
  hipLaunchKernelGGL(prep_compact, dim3(nblk), dim3(256), 0, stream,
                     W1, W2, W3, W4, wt1, wt2, wt3, w4h,
                     species, idxloc, cnt, out, natoms, nprep);

  const int nblocks = (natoms + 63) / 64;  // worst case; surplus blocks exit early
  hipLaunchKernelGGL(mlp_kernel, dim3(nblocks), dim3(512), 0, stream,
                     X, species, wt1, b1, wt2, b2, wt3, b3, w4h, b4, out, natoms,
                     use_compact ? idxloc : (const int*)nullptr,
                     use_compact ? (const int*)cnt : (const int*)nullptr, nchunks);
}

// Round 13
// 344.312 us; speedup vs baseline: 1.3229x; 1.3229x over previous
//
#include <hip/hip_runtime.h>

typedef _Float16 half8 __attribute__((ext_vector_type(8)));
typedef _Float16 half4 __attribute__((ext_vector_type(4)));
typedef float f32x4 __attribute__((ext_vector_type(4)));
typedef float f32x16 __attribute__((ext_vector_type(16)));

#define CHUNK 1024
#define NCHUNK_MAX 512  // supports up to 524288 atoms in compact mode

// ---------------- prologue: weights retile + chunk-local compaction --------
// One dispatch, two block roles:
//   blocks [0, nprep): cast + retile weights to fp16 MFMA tiles.
//   blocks [nprep, nprep+nchunks): chunk c (1024 atoms) self-compacts into
//     idxloc[c*1024 ...] and writes cnt[c]. No atomics -> no memset, no
//     extra dispatch (R15: each dispatch costs ~25us on this bench).
__global__ void prep_compact(const float* __restrict__ W1, const float* __restrict__ W2,
                             const float* __restrict__ W3, const float* __restrict__ W4,
                             _Float16* __restrict__ wt1, _Float16* __restrict__ wt2,
                             _Float16* __restrict__ wt3, _Float16* __restrict__ w4h,
                             const int* __restrict__ species, int* __restrict__ idxloc,
                             int* __restrict__ cnt, float* __restrict__ out,
                             int natoms, int nprep) {
  __shared__ int wsum[4];
  if (blockIdx.x >= nprep) {
    // ---- chunk-local compaction: 1024 atoms, 256 threads, 4 sub-rounds ----
    const int c = blockIdx.x - nprep;
    const int lane = threadIdx.x & 63, w = threadIdx.x >> 6;
    int base = 0;
#pragma unroll 1
    for (int j = 0; j < 4; ++j) {
      const int i = c * CHUNK + j * 256 + threadIdx.x;
      const bool valid = (i < natoms) && (species[i] >= 0);
      const unsigned long long m = __ballot(valid);
      if (lane == 0) wsum[w] = (int)__popcll(m);
      __syncthreads();
      int wb = base;
#pragma unroll
      for (int k = 0; k < 4; ++k)
        if (k < w) wb += wsum[k];
      if (valid) {
        int off = (int)__popcll(m & ((1ull << lane) - 1));
        idxloc[c * CHUNK + wb + off] = i;
      } else if (i < natoms) {
        out[i] = 0.0f;  // masked atoms must be exactly 0
      }
      base += wsum[0] + wsum[1] + wsum[2] + wsum[3];
      __syncthreads();  // wsum reused next round
    }
    if (threadIdx.x == 0) cnt[c] = base;
    return;
  }
  // ---- weight retile (unchanged math) ----
  int idx = blockIdx.x * blockDim.x + threadIdx.x;
  if (idx < 512 * 256) {  // W1: K=256, N=512, KS=16
    int k = idx >> 9, n = idx & 511;
    int off = (((n >> 5) * 16 + (k >> 4)) << 9) + (n & 31) * 8 + (((k >> 3) & 1) << 8) + (k & 7);
    wt1[off] = (_Float16)W1[idx];
    return;
  }
  int i2 = idx - 512 * 256;
  if (i2 < 512 * 512) {  // W2: K=512, N=512, KS=32
    int k = i2 >> 9, n = i2 & 511;
    int off = (((n >> 5) * 32 + (k >> 4)) << 9) + (n & 31) * 8 + (((k >> 3) & 1) << 8) + (k & 7);
    wt2[off] = (_Float16)W2[i2];
    return;
  }
  int i3 = i2 - 512 * 512;
  if (i3 < 512 * 256) {  // W3: K=512, N=256, KS=32
    int k = i3 >> 8, n = i3 & 255;
    int off = (((n >> 5) * 32 + (k >> 4)) << 9) + (n & 31) * 8 + (((k >> 3) & 1) << 8) + (k & 7);
    wt3[off] = (_Float16)W3[i3];
    return;
  }
  int i4 = i3 - 512 * 256;
  if (i4 < 256) w4h[i4] = (_Float16)W4[i4];
}

// silu with raw v_rcp_f32 (no IEEE div sequence); ~1ulp, well within tolerance
__device__ __forceinline__ float fast_silu(float s) {
  float e = __expf(-s);
  float d = 1.0f + e;
  float r;
  asm("v_rcp_f32 %0, %1" : "=v"(r) : "v"(d));
  return s * r;
}

// ---------------- fused MLP ----------------
// R8 geometry (verified local optimum): 64 atoms/block, 512 threads = 8
// waves, FT=2, AT=2, acc 64 AGPR + 64 arch VGPR = EXACTLY the 128-reg
// budget at 4 waves/EU; 2 blocks/CU -> 16 waves/CU in TWO independent
// barrier domains (R13: merging them costs 16%).
// Evidence: R9 FAILED (L3 prefetch thrash). R10 NEUTRAL (kept). R11
// falsified skew. R12 falsified 8 waves/CU. R13 falsified single-domain.
// R14 FAILED (in_sizes is elements). R15: dispatches cost ~25us each.
// R16 WIN (360): dispatch-free compaction. R17 WIN (352.6): CHUNK=1024 +
// L4 fused into L3 epilogue. R18 small WIN (350.3): NT X-loads. R19 WIN
// (343.9): cross-layer A-prefetch, VGPR held at 64.
// R20 FAILED (455): K-loop unroll 4 -> live ranges exceeded the pinned
// 128-reg budget -> SCRATCH SPILL (WRITE_SIZE 1.6->249MB despite
// VGPR_Count 64 — launch_bounds pins the count; spill shows in
// WRITE_SIZE). The unroll axis is dead, like prefetch-depth (R12),
// for the same reason: zero register headroom.
// R21: clean revert to R19 (the verified 343.9us kernel).

#define MFMA(a, b, c) __builtin_amdgcn_mfma_f32_32x32x16_f16(a, b, c, 0, 0, 0)

// A0: preloaded first A-fragments (ks=0) for THIS layer.
// If NFT>0: before the epilogue, load next layer's first A-fragments
// (wfeat stride NKS) into Anext.
template <int FT, int AT, int KS, int PIN, int POUT, int NFT, int NKS>
__device__ __forceinline__ void layer(const _Float16* __restrict__ wt,
                                      const float* __restrict__ bias,
                                      char* __restrict__ Hb,
                                      int wfeat, int lane,
                                      const half8* __restrict__ A0,
                                      const _Float16* __restrict__ next_wt,
                                      half8* __restrict__ Anext) {
  const int lr = lane & 31;
  const int lh = lane >> 5;
  const int n0 = wfeat * (FT * 32);
  const int s0 = (lr & 31) << 4;  // row swizzle; (a*32+lr)&31 == lr&31
  const char* Bp = Hb + lr * PIN;
  const char* wp = (const char*)wt + (size_t)(wfeat * FT * KS) * 1024 + lh * 512 + lr * 16;

  // init acc = bias (folds epilogue bias-add into MFMA C-in; bv transient)
  f32x16 acc[FT][AT];
#pragma unroll
  for (int f = 0; f < FT; ++f)
#pragma unroll
    for (int rg = 0; rg < 4; ++rg) {
      const int feat = n0 + f * 32 + rg * 8 + lh * 4;
      const f32x4 bv = *(const f32x4*)(bias + feat);
#pragma unroll
      for (int a = 0; a < AT; ++a)
#pragma unroll
        for (int r = 0; r < 4; ++r) acc[f][a][rg * 4 + r] = bv[r];
    }

  half8 Af[FT], Ag[FT], Bf[AT], Bg[AT];
#pragma unroll
  for (int f = 0; f < FT; ++f) Af[f] = A0[f];  // preloaded (R19)
#pragma unroll
  for (int a = 0; a < AT; ++a)
    Bf[a] = *(const half8*)(Bp + a * 32 * PIN + ((lh * 16) ^ s0));

#pragma unroll 1
  for (int ks = 0; ks < KS - 2; ks += 2) {
#pragma unroll
    for (int f = 0; f < FT; ++f)
      Ag[f] = *(const half8*)(wp + f * (KS * 1024) + (ks + 1) * 1024);
#pragma unroll
    for (int a = 0; a < AT; ++a)
      Bg[a] = *(const half8*)(Bp + a * 32 * PIN + (((ks + 1) * 32 + lh * 16) ^ s0));
#pragma unroll
    for (int f = 0; f < FT; ++f)
#pragma unroll
      for (int a = 0; a < AT; ++a) acc[f][a] = MFMA(Af[f], Bf[a], acc[f][a]);
#pragma unroll
    for (int f = 0; f < FT; ++f)
      Af[f] = *(const half8*)(wp + f * (KS * 1024) + (ks + 2) * 1024);
#pragma unroll
    for (int a = 0; a < AT; ++a)
      Bf[a] = *(const half8*)(Bp + a * 32 * PIN + (((ks + 2) * 32 + lh * 16) ^ s0));
#pragma unroll
    for (int f = 0; f < FT; ++f)
#pragma unroll
      for (int a = 0; a < AT; ++a) acc[f][a] = MFMA(Ag[f], Bg[a], acc[f][a]);
  }
#pragma unroll
  for (int f = 0; f < FT; ++f)
    Ag[f] = *(const half8*)(wp + f * (KS * 1024) + (KS - 1) * 1024);
#pragma unroll
  for (int a = 0; a < AT; ++a)
    Bg[a] = *(const half8*)(Bp + a * 32 * PIN + ((((KS - 1) * 32) + lh * 16) ^ s0));
#pragma unroll
  for (int f = 0; f < FT; ++f)
#pragma unroll
    for (int a = 0; a < AT; ++a) acc[f][a] = MFMA(Af[f], Bf[a], acc[f][a]);
#pragma unroll
  for (int f = 0; f < FT; ++f)
#pragma unroll
    for (int a = 0; a < AT; ++a) acc[f][a] = MFMA(Ag[f], Bg[a], acc[f][a]);

  // R19: issue next layer's first A-loads NOW — latency hides under the
  // silu + barrier + epilogue-write phase. Buffer regs Af/Ag are dead
  // after the tail; Anext reuses that budget.
  if constexpr (NFT > 0) {
    const char* wpn = (const char*)next_wt + (size_t)(wfeat * NFT * NKS) * 1024 + lh * 512 + lr * 16;
#pragma unroll
    for (int f = 0; f < NFT; ++f)
      Anext[f] = *(const half8*)(wpn + f * (NKS * 1024));
  }

  // silu in-place BEFORE the barrier (R10).
#pragma unroll
  for (int f = 0; f < FT; ++f)
#pragma unroll
    for (int a = 0; a < AT; ++a)
#pragma unroll
      for (int j = 0; j < 16; ++j) acc[f][a][j] = fast_silu(acc[f][a][j]);

  __syncthreads();  // all waves done reading input region; safe to overwrite

  // post-barrier: cvt -> fp16, write swizzled (2-way, free)
#pragma unroll
  for (int f = 0; f < FT; ++f) {
#pragma unroll
    for (int rg = 0; rg < 4; ++rg) {
      const int feat = n0 + f * 32 + rg * 8 + lh * 4;
#pragma unroll
      for (int a = 0; a < AT; ++a) {
        half4 h;
#pragma unroll
        for (int r = 0; r < 4; ++r) h[r] = (_Float16)acc[f][a][rg * 4 + r];
        const int row = a * 32 + lr;
        *(half4*)(Hb + row * POUT + ((feat * 2) ^ ((row & 31) << 4))) = h;
      }
    }
  }
}

extern "C" __global__ void __launch_bounds__(512, 4)
mlp_kernel(const float* __restrict__ X, const int* __restrict__ species,
           const _Float16* __restrict__ wt1, const float* __restrict__ b1,
           const _Float16* __restrict__ wt2, const float* __restrict__ b2,
           const _Float16* __restrict__ wt3, const float* __restrict__ b3,
           const _Float16* __restrict__ w4h, const float* __restrict__ b4,
           float* __restrict__ out, int natoms,
           const int* __restrict__ idxloc, const int* __restrict__ cnt, int nchunks) {
  __shared__ __align__(16) char H[64 * 1024];
  __shared__ int prefixS[NCHUNK_MAX + 1];  // exclusive chunk starts
  __shared__ int gidx[64];                 // source atom per staged row
  __shared__ int wtot[8];
  const int tid = threadIdx.x;
  const int lane = tid & 63;
  const int wid = tid >> 6;  // 8 feature-slice waves
  const long abase = (long)blockIdx.x * 64;

  // R19: L1 first-A preload at kernel entry — latency hides under the
  // scan + staging phase. Harmless for early-exit blocks.
  half8 A1[2], A2[2], A3[1];
  {
    const char* wp1 = (const char*)wt1 + (size_t)(wid * 2 * 16) * 1024 +
                      (lane >> 5) * 512 + (lane & 31) * 16;
    A1[0] = *(const half8*)(wp1);
    A1[1] = *(const half8*)(wp1 + 16 * 1024);
  }

  int nvalid = natoms;
  if (idxloc) {
    // ---- per-block prefix scan of cnt[] (nchunks <= 512, 1 per thread) ----
    int v = (tid < nchunks) ? cnt[tid] : 0;
    int ws_ = v;
#pragma unroll
    for (int d = 1; d < 64; d <<= 1) {
      int o = __shfl_up(ws_, d);
      if (lane >= d) ws_ += o;
    }
    if (lane == 63) wtot[wid] = ws_;
    __syncthreads();
    int wbase = 0, tot = 0;
#pragma unroll
    for (int k = 0; k < 8; ++k) {
      if (k < wid) wbase += wtot[k];
      tot += wtot[k];
    }
    if (tid < nchunks) prefixS[tid] = wbase + ws_ - v;  // exclusive
    nvalid = tot;
    __syncthreads();  // prefixS ready
    if (abase >= nvalid) return;  // uniform whole-block exit
  }

  // ---- stage X[64x256] -> fp16 LDS, pitch 512B, swizzled ----
  // NT loads: X rows touched exactly once -> evict-first keeps weights
  // L2-resident (R18).
  {
    const int r = tid >> 3, cg = tid & 7;
    long li = abase + r;
    const long lmax = (long)nvalid - 1;
    if (li > lmax) li = lmax;  // clamp: pad rows read a valid row, never stored
    long g = li;
    if (idxloc) {
      int lo = 0, hi = nchunks - 1;  // largest c with prefixS[c] <= li
      while (lo < hi) {
        int mid = (lo + hi + 1) >> 1;
        if (prefixS[mid] <= (int)li) lo = mid; else hi = mid - 1;
      }
      g = idxloc[lo * CHUNK + ((int)li - prefixS[lo])];
      if (cg == 0) gidx[r] = (int)g;
    }
    const float* xp = X + g * 256;
    const int sw = (r & 31) << 4;
#pragma unroll
    for (int j = 0; j < 8; ++j) {
      const int colh = cg * 4 + j * 32;
      f32x4 v = __builtin_nontemporal_load((const f32x4*)(xp + colh));
      half4 h;
#pragma unroll
      for (int e = 0; e < 4; ++e) h[e] = (_Float16)v[e];
      *(half4*)(H + r * 512 + ((colh * 2) ^ sw)) = h;
    }
  }
  __syncthreads();

  // L1: Xh[64x256] -> H1[64x512]; prefetches L2's first A into A2
  layer<2, 2, 16, 512, 1024, 2, 32>(wt1, b1, H, wid, lane, A1, wt2, A2);
  __syncthreads();
  // L2: H1 -> H2[64x512]; prefetches L3's first A into A3
  layer<2, 2, 32, 1024, 1024, 1, 32>(wt2, b2, H, wid, lane, A2, wt3, A3);
  __syncthreads();

  // ---- L3 (FT=1, AT=2, KS=32) with L4 fused into the register epilogue ----
  {
    const int lr = lane & 31;
    const int lh = lane >> 5;
    const int n0 = wid * 32;
    const int s0 = (lr & 31) << 4;
    const char* Bp = H + lr * 1024;
    const char* wp = (const char*)wt3 + (size_t)(wid * 32) * 1024 + lh * 512 + lr * 16;

    f32x16 acc[2];
#pragma unroll
    for (int rg = 0; rg < 4; ++rg) {
      const int feat = n0 + rg * 8 + lh * 4;
      const f32x4 bv = *(const f32x4*)(b3 + feat);
#pragma unroll
      for (int a = 0; a < 2; ++a)
#pragma unroll
        for (int r = 0; r < 4; ++r) acc[a][rg * 4 + r] = bv[r];
    }

    half8 Af, Ag, Bf[2], Bg[2];
    Af = A3[0];  // preloaded by L2 (R19)
#pragma unroll
    for (int a = 0; a < 2; ++a)
      Bf[a] = *(const half8*)(Bp + a * 32 * 1024 + ((lh * 16) ^ s0));

#pragma unroll 1
    for (int ks = 0; ks < 30; ks += 2) {
      Ag = *(const half8*)(wp + (ks + 1) * 1024);
#pragma unroll
      for (int a = 0; a < 2; ++a)
        Bg[a] = *(const half8*)(Bp + a * 32 * 1024 + (((ks + 1) * 32 + lh * 16) ^ s0));
#pragma unroll
      for (int a = 0; a < 2; ++a) acc[a] = MFMA(Af, Bf[a], acc[a]);
      Af = *(const half8*)(wp + (ks + 2) * 1024);
#pragma unroll
      for (int a = 0; a < 2; ++a)
        Bf[a] = *(const half8*)(Bp + a * 32 * 1024 + (((ks + 2) * 32 + lh * 16) ^ s0));
#pragma unroll
      for (int a = 0; a < 2; ++a) acc[a] = MFMA(Ag, Bg[a], acc[a]);
    }
    Ag = *(const half8*)(wp + 31 * 1024);
#pragma unroll
    for (int a = 0; a < 2; ++a)
      Bg[a] = *(const half8*)(Bp + a * 32 * 1024 + ((31 * 32 + lh * 16) ^ s0));
#pragma unroll
    for (int a = 0; a < 2; ++a) acc[a] = MFMA(Af, Bf[a], acc[a]);
#pragma unroll
    for (int a = 0; a < 2; ++a) acc[a] = MFMA(Ag, Bg[a], acc[a]);

    // silu + in-register dot with w4 slice (feats n0+rg*8+lh*4+r)
    float s[2] = {0.0f, 0.0f};
#pragma unroll
    for (int rg = 0; rg < 4; ++rg) {
      half4 wv = *(const half4*)(w4h + n0 + rg * 8 + lh * 4);
#pragma unroll
      for (int r = 0; r < 4; ++r) {
        const float wf = (float)wv[r];
#pragma unroll
        for (int a = 0; a < 2; ++a)
          s[a] += fast_silu(acc[a][rg * 4 + r]) * wf;
      }
    }
    // combine the two feat-halves (lh=0/1) held by lanes lr and lr+32
    s[0] += __shfl_xor(s[0], 32);
    s[1] += __shfl_xor(s[1], 32);

    __syncthreads();  // all waves done reading H2 -> safe to overwrite with P
    float* P = (float*)H;  // P[atom][8] partials, 2KB
    if (lh == 0) {
      P[(0 * 32 + lr) * 8 + wid] = s[0];
      P[(1 * 32 + lr) * 8 + wid] = s[1];
    }
  }
  __syncthreads();

  // final reduce: out[atom] = sum_w P[atom][w] + b4
  {
    const float* P = (const float*)H;
    const int atom = tid >> 3, part = tid & 7;
    float sum = P[atom * 8 + part];
    sum += __shfl_xor(sum, 1);
    sum += __shfl_xor(sum, 2);
    sum += __shfl_xor(sum, 4);
    if (part == 0) {
      const long li = abase + atom;
      if (li < nvalid) {
        float r = sum + b4[0];
        if (idxloc) {
          __builtin_nontemporal_store(r, &out[gidx[atom]]);  // masked zeroed in prep
        } else {
          float v = (species[li] >= 0) ? r : 0.0f;
          __builtin_nontemporal_store(v, &out[li]);
        }
      }
    }
  }
}

extern "C" void kernel_launch(void* const* d_in, const int* in_sizes, int n_in,
                              void* d_out, int out_size, void* d_ws, size_t ws_size,
                              hipStream_t stream) {
  const float* X = (const float*)d_in[0];
  const int* species = (const int*)d_in[1];
  const float* W1 = (const float*)d_in[2];
  const float* b1 = (const float*)d_in[3];
  const float* W2 = (const float*)d_in[4];
  const float* b2 = (const float*)d_in[5];
  const float* W3 = (const float*)d_in[6];
  const float* b3 = (const float*)d_in[7];
  const float* W4 = (const float*)d_in[8];
  const float* b4 = (const float*)d_in[9];
  float* out = (float*)d_out;
  const int natoms = in_sizes[0] / 256;  // in_sizes is ELEMENTS (R14 lesson)

  char* ws = (char*)d_ws;
  _Float16* wt1 = (_Float16*)(ws);                             // 512*256*2 B
  _Float16* wt2 = (_Float16*)(ws + 262144);                    // 512*512*2 B
  _Float16* wt3 = (_Float16*)(ws + 262144 + 524288);           // 256*512*2 B
  _Float16* w4h = (_Float16*)(ws + 262144 + 524288 + 262144);  // 512 B
  int* cnt = (int*)(ws + 1049088);                             // nchunks*4 B
  int* idxloc = (int*)(ws + 1049088 + 4096);                   // natoms*4 B (padded region)

  const int nchunks = (natoms + CHUNK - 1) / CHUNK;
  const size_t ws_needed = 1049088 + 4096 + (size_t)nchunks * CHUNK * 4;
  const bool use_compact = (ws_size >= ws_needed) && (nchunks <= NCHUNK_MAX);

  const int prep_total = 512 * 256 + 512 * 512 + 256 * 512 + 256;
  const int nprep = (prep_total + 255) / 256;
  const int nblk = nprep + (use_compact ? nchunks : 0);
  hipLaunchKernelGGL(prep_compact, dim3(nblk), dim3(256), 0, stream,
                     W1, W2, W3, W4, wt1, wt2, wt3, w4h,
                     species, idxloc, cnt, out, natoms, nprep);

  const int nblocks = (natoms + 63) / 64;  // worst case; surplus blocks exit early
  hipLaunchKernelGGL(mlp_kernel, dim3(nblocks), dim3(512), 0, stream,
                     X, species, wt1, b1, wt2, b2, wt3, b3, w4h, b4, out, natoms,
                     use_compact ? idxloc : (const int*)nullptr,
                     use_compact ? (const int*)cnt : (const int*)nullptr, nchunks);
}